// Round 1
// baseline (538.171 us; speedup 1.0000x reference)
//
#include <hip/hip_runtime.h>
#include <math.h>
#include <stdint.h>

#define N_NODES 50000
#define N_EDGES 800000
#define IN_DIM  512
#define OUT_DIM 256

// ---------------- K1: el/er scalar projections (one wave per node) ----------
__global__ __launch_bounds__(256) void proj_lr(const float* __restrict__ feat,
                      const float* __restrict__ Wl, const float* __restrict__ bl,
                      const float* __restrict__ Wr, const float* __restrict__ br,
                      float* __restrict__ el, float* __restrict__ er) {
  int wave = (int)((blockIdx.x * blockDim.x + threadIdx.x) >> 6);
  int lane = threadIdx.x & 63;
  if (wave >= N_NODES) return;
  const float4* frow = (const float4*)(feat + (size_t)wave * IN_DIM);
  const float4* wl4  = (const float4*)Wl;
  const float4* wr4  = (const float4*)Wr;
  float al = 0.f, ar = 0.f;
  #pragma unroll
  for (int j = lane; j < IN_DIM / 4; j += 64) {
    float4 f = frow[j];
    float4 a = wl4[j];
    float4 c = wr4[j];
    al += f.x * a.x + f.y * a.y + f.z * a.z + f.w * a.w;
    ar += f.x * c.x + f.y * c.y + f.z * c.z + f.w * c.w;
  }
  #pragma unroll
  for (int o = 32; o > 0; o >>= 1) {
    al += __shfl_xor(al, o);
    ar += __shfl_xor(ar, o);
  }
  if (lane == 0) {
    el[wave] = al + bl[0];
    er[wave] = ar + br[0];
  }
}

// ---------------- K2: ft = feat @ W + b  (fp32 tiled, BM=32) ----------------
#define BM  32
#define BKC 128
__global__ __launch_bounds__(256) void gemm_ft(const float* __restrict__ feat,
                        const float* __restrict__ W, const float* __restrict__ b,
                        float* __restrict__ ft) {
  __shared__ float tile[BM][BKC];   // 16 KB
  const int t    = threadIdx.x;
  const int row0 = blockIdx.x * BM;
  const int colb = (t & 63) * 4;     // 64 col-threads * 4 cols = 256
  const int rowb = (t >> 6) * 8;     // 4 waves * 8 rows = 32

  float acc[8][4];
  #pragma unroll
  for (int r = 0; r < 8; ++r)
    #pragma unroll
    for (int j = 0; j < 4; ++j) acc[r][j] = 0.f;

  for (int k0 = 0; k0 < IN_DIM; k0 += BKC) {
    // cooperative load of 32x128 feat tile (float4, coalesced)
    #pragma unroll
    for (int i = t; i < BM * (BKC / 4); i += 256) {
      int r = i / (BKC / 4);
      int c = (i % (BKC / 4)) * 4;
      int gr = row0 + r;
      float4 v = make_float4(0.f, 0.f, 0.f, 0.f);
      if (gr < N_NODES)
        v = *(const float4*)(feat + (size_t)gr * IN_DIM + k0 + c);
      *(float4*)&tile[r][c] = v;
    }
    __syncthreads();
    #pragma unroll 4
    for (int k = 0; k < BKC; k += 4) {
      float4 w0 = *(const float4*)(W + (size_t)(k0 + k + 0) * OUT_DIM + colb);
      float4 w1 = *(const float4*)(W + (size_t)(k0 + k + 1) * OUT_DIM + colb);
      float4 w2 = *(const float4*)(W + (size_t)(k0 + k + 2) * OUT_DIM + colb);
      float4 w3 = *(const float4*)(W + (size_t)(k0 + k + 3) * OUT_DIM + colb);
      #pragma unroll
      for (int r = 0; r < 8; ++r) {
        float4 f = *(const float4*)&tile[rowb + r][k];   // wave-uniform: LDS broadcast
        acc[r][0] += f.x * w0.x + f.y * w1.x + f.z * w2.x + f.w * w3.x;
        acc[r][1] += f.x * w0.y + f.y * w1.y + f.z * w2.y + f.w * w3.y;
        acc[r][2] += f.x * w0.z + f.y * w1.z + f.z * w2.z + f.w * w3.z;
        acc[r][3] += f.x * w0.w + f.y * w1.w + f.z * w2.w + f.w * w3.w;
      }
    }
    __syncthreads();
  }
  float4 bb = *(const float4*)(b + colb);
  #pragma unroll
  for (int r = 0; r < 8; ++r) {
    int gr = row0 + rowb + r;
    if (gr < N_NODES) {
      float4 o;
      o.x = acc[r][0] + bb.x;
      o.y = acc[r][1] + bb.y;
      o.z = acc[r][2] + bb.z;
      o.w = acc[r][3] + bb.w;
      *(float4*)(ft + (size_t)gr * OUT_DIM + colb) = o;
    }
  }
}

// ---------------- K3: degree histogram --------------------------------------
__global__ void deg_count(const int* __restrict__ dst, int* __restrict__ deg) {
  int e = blockIdx.x * blockDim.x + threadIdx.x;
  if (e < N_EDGES) atomicAdd(&deg[dst[e]], 1);
}

// ---------------- K4: exclusive scan (single block) -------------------------
__global__ __launch_bounds__(1024) void scan_off(const int* __restrict__ deg,
                                                 int* __restrict__ off) {
  __shared__ int buf[1024];
  const int t = threadIdx.x;
  int carry = 0;
  for (int base = 0; base < N_NODES; base += 1024) {
    int i = base + t;
    int v = (i < N_NODES) ? deg[i] : 0;
    buf[t] = v;
    __syncthreads();
    for (int d = 1; d < 1024; d <<= 1) {
      int x = (t >= d) ? buf[t - d] : 0;
      __syncthreads();
      buf[t] += x;
      __syncthreads();
    }
    if (i < N_NODES) off[i] = carry + buf[t] - v;   // exclusive
    int total = buf[1023];
    __syncthreads();                                // before next chunk overwrites buf
    carry += total;
  }
  if (t == 0) off[N_NODES] = carry;                 // == N_EDGES
}

// ---------------- K5: scatter edges into CSR + edge score -------------------
__global__ void scatter_edges(const int* __restrict__ src, const int* __restrict__ dst,
                              const float* __restrict__ el, const float* __restrict__ er,
                              const int* __restrict__ off, int* __restrict__ cnt,
                              int* __restrict__ ssrc, float* __restrict__ se) {
  int e = blockIdx.x * blockDim.x + threadIdx.x;
  if (e >= N_EDGES) return;
  int s = src[e], d = dst[e];
  int pos = off[d] + atomicAdd(&cnt[d], 1);
  float ev = el[s] + er[d];
  ev = (ev > 0.f ? ev : 0.f) + 1.0f;
  ssrc[pos] = s;
  se[pos]   = ev;
}

// ---------------- K6: per-dst softmax + weighted aggregation ----------------
__global__ __launch_bounds__(256) void aggregate(const int* __restrict__ off,
                         const int* __restrict__ ssrc, const float* __restrict__ se,
                         const float* __restrict__ ft, float* __restrict__ out) {
  int wave = (int)((blockIdx.x * blockDim.x + threadIdx.x) >> 6);
  int lane = threadIdx.x & 63;
  if (wave >= N_NODES) return;
  int start = off[wave], end = off[wave + 1];
  float4 acc = make_float4(0.f, 0.f, 0.f, 0.f);
  if (end > start) {
    float m = -1e30f;
    for (int i = start + lane; i < end; i += 64) m = fmaxf(m, se[i]);
    #pragma unroll
    for (int o = 32; o > 0; o >>= 1) m = fmaxf(m, __shfl_xor(m, o));
    float dsum = 0.f;
    for (int i = start + lane; i < end; i += 64) dsum += __expf(se[i] - m);
    #pragma unroll
    for (int o = 32; o > 0; o >>= 1) dsum += __shfl_xor(dsum, o);
    float inv = 1.0f / dsum;
    for (int i = start; i < end; ++i) {     // uniform per-edge loop
      float w = __expf(se[i] - m) * inv;
      int s = ssrc[i];
      const float4* frow = (const float4*)(ft + (size_t)s * OUT_DIM);
      float4 v = frow[lane];
      acc.x += w * v.x; acc.y += w * v.y; acc.z += w * v.z; acc.w += w * v.w;
    }
  }
  ((float4*)(out + (size_t)wave * OUT_DIM))[lane] = acc;
}

// ---------------- launch ----------------------------------------------------
extern "C" void kernel_launch(void* const* d_in, const int* in_sizes, int n_in,
                              void* d_out, int out_size, void* d_ws, size_t ws_size,
                              hipStream_t stream) {
  const float* feat = (const float*)d_in[0];
  // d_in[1] = p  (unused in eval path)
  const float* Wl = (const float*)d_in[2];
  const float* bl = (const float*)d_in[3];
  const float* Wr = (const float*)d_in[4];
  const float* br = (const float*)d_in[5];
  const float* W  = (const float*)d_in[6];
  const float* b  = (const float*)d_in[7];
  const int* src  = (const int*)d_in[8];
  const int* dst  = (const int*)d_in[9];
  float* out = (float*)d_out;

  char* ws = (char*)d_ws;
  float* el = (float*)ws;  ws += (size_t)N_NODES * 4;
  float* er = (float*)ws;  ws += (size_t)N_NODES * 4;
  float* ft = (float*)ws;  ws += (size_t)N_NODES * OUT_DIM * 4;
  int* deg  = (int*)ws;    ws += (size_t)N_NODES * 4;
  int* cnt  = (int*)ws;    ws += (size_t)N_NODES * 4;
  int* off  = (int*)ws;    ws += (size_t)(N_NODES + 1) * 4;
  int* ssrc = (int*)ws;    ws += (size_t)N_EDGES * 4;
  float* se = (float*)ws;  ws += (size_t)N_EDGES * 4;

  // zero deg + cnt (adjacent)
  hipMemsetAsync(deg, 0, (size_t)N_NODES * 4 * 2, stream);

  proj_lr<<<(N_NODES + 3) / 4, 256, 0, stream>>>(feat, Wl, bl, Wr, br, el, er);
  gemm_ft<<<(N_NODES + BM - 1) / BM, 256, 0, stream>>>(feat, W, b, ft);
  deg_count<<<(N_EDGES + 255) / 256, 256, 0, stream>>>(dst, deg);
  scan_off<<<1, 1024, 0, stream>>>(deg, off);
  scatter_edges<<<(N_EDGES + 255) / 256, 256, 0, stream>>>(src, dst, el, er, off, cnt, ssrc, se);
  aggregate<<<(N_NODES + 3) / 4, 256, 0, stream>>>(off, ssrc, se, ft, out);
}

// Round 5
// 246.579 us; speedup vs baseline: 2.1826x; 2.1826x over previous
//
#include <hip/hip_runtime.h>
#include <math.h>
#include <stdint.h>

#define N_NODES 50000
#define N_EDGES 800000
#define IN_DIM  512
#define OUT_DIM 256
#define NBLK_SCAN 49   // ceil(50000/1024)

typedef __attribute__((ext_vector_type(8))) short short8;
typedef __attribute__((ext_vector_type(4))) float f32x4;

__device__ inline unsigned short f2bf(float x) {
  unsigned u = __float_as_uint(x);
  unsigned r = (u + 0x7FFFu + ((u >> 16) & 1u)) >> 16;   // RNE
  return (unsigned short)r;
}
__device__ inline float bf2f(unsigned short h) {
  return __uint_as_float(((unsigned)h) << 16);
}

// ---------------- K1: el/er scalar projections (one wave per node) ----------
__global__ __launch_bounds__(256) void proj_lr(const float* __restrict__ feat,
                      const float* __restrict__ Wl, const float* __restrict__ bl,
                      const float* __restrict__ Wr, const float* __restrict__ br,
                      float* __restrict__ el, float* __restrict__ er) {
  int wave = (int)((blockIdx.x * blockDim.x + threadIdx.x) >> 6);
  int lane = threadIdx.x & 63;
  if (wave >= N_NODES) return;
  const float4* frow = (const float4*)(feat + (size_t)wave * IN_DIM);
  const float4* wl4  = (const float4*)Wl;
  const float4* wr4  = (const float4*)Wr;
  float al = 0.f, ar = 0.f;
  #pragma unroll
  for (int j = lane; j < IN_DIM / 4; j += 64) {
    float4 f = frow[j];
    float4 a = wl4[j];
    float4 c = wr4[j];
    al += f.x * a.x + f.y * a.y + f.z * a.z + f.w * a.w;
    ar += f.x * c.x + f.y * c.y + f.z * c.z + f.w * c.w;
  }
  #pragma unroll
  for (int o = 32; o > 0; o >>= 1) {
    al += __shfl_xor(al, o);
    ar += __shfl_xor(ar, o);
  }
  if (lane == 0) {
    el[wave] = al + bl[0];
    er[wave] = ar + br[0];
  }
}

// ---------------- K2a: W [512][256] fp32 -> Wt [256][512] bf16 --------------
__global__ __launch_bounds__(256) void wconv(const float* __restrict__ W,
                                             unsigned short* __restrict__ Wt) {
  int i = blockIdx.x * 256 + threadIdx.x;   // over 131072
  int c = i >> 9, k = i & 511;
  Wt[i] = f2bf(W[(size_t)k * OUT_DIM + c]);
}

// ---------------- K2b: ft = bf16( feat @ W + b )  via MFMA ------------------
// block: 512 threads = 8 waves; tile BM=128 rows x full N=256.
// Wave wm owns rows [m0+wm*16, +16), all 256 cols (16 n-tiles of 16).
// mfma(Xfrag=W-cols, Yfrag=feat-rows, acc): D[ i=(l>>4)*4+reg -> W col ]
//                                            [ j=l&15        -> feat row ]
#define GBM 128
#define GBK 64
__global__ __launch_bounds__(512) void gemm_mfma(const float* __restrict__ feat,
                        const unsigned short* __restrict__ Wt,
                        const float* __restrict__ bias,
                        unsigned short* __restrict__ ftb) {
  __shared__ unsigned short Bs[OUT_DIM * GBK];   // 32 KB, XOR-swizzled rows of 128B
  const int tid  = threadIdx.x;
  const int lane = tid & 63;
  const int wm   = tid >> 6;          // 0..7
  const int m0   = blockIdx.x * GBM;

  f32x4 acc[16];
  #pragma unroll
  for (int nt = 0; nt < 16; ++nt) acc[nt] = (f32x4)0.f;

  int row  = m0 + wm * 16 + (lane & 15);
  int rowc = row < N_NODES ? row : N_NODES - 1;
  const float* fr = feat + (size_t)rowc * IN_DIM;
  const int kgrp = (lane >> 4);       // 0..3

  for (int k0 = 0; k0 < IN_DIM; k0 += GBK) {
    // stage Wt[0..255][k0..k0+64) into LDS (bf16, swizzled)
    #pragma unroll
    for (int i = tid; i < OUT_DIM * GBK / 8; i += 512) {   // 2048 x 16B chunks
      int c = i >> 3, o = i & 7;
      uint4 v = *(const uint4*)(Wt + (size_t)c * IN_DIM + k0 + o * 8);
      int boff = (c * 128 + o * 16) ^ ((c & 7) << 4);
      *(uint4*)((char*)Bs + boff) = v;
    }
    __syncthreads();

    #pragma unroll
    for (int kk = 0; kk < GBK; kk += 32) {
      // feat fragment: 8 consecutive fp32 -> bf16x8
      int kb = k0 + kk + kgrp * 8;
      float4 a0 = *(const float4*)(fr + kb);
      float4 a1 = *(const float4*)(fr + kb + 4);
      short8 yf;
      yf[0] = (short)f2bf(a0.x); yf[1] = (short)f2bf(a0.y);
      yf[2] = (short)f2bf(a0.z); yf[3] = (short)f2bf(a0.w);
      yf[4] = (short)f2bf(a1.x); yf[5] = (short)f2bf(a1.y);
      yf[6] = (short)f2bf(a1.z); yf[7] = (short)f2bf(a1.w);
      int kloc = kk * 2 + kgrp * 16;    // byte offset inside 128B row
      #pragma unroll
      for (int nt = 0; nt < 16; ++nt) {
        int c = nt * 16 + (lane & 15);
        int boff = (c * 128 + kloc) ^ ((c & 7) << 4);
        short8 xf = *(const short8*)((const char*)Bs + boff);
        acc[nt] = __builtin_amdgcn_mfma_f32_16x16x32_bf16(xf, yf, acc[nt], 0, 0, 0);
      }
    }
    __syncthreads();
  }

  // store: acc[nt][reg] = ft[row=m0+wm*16+(l&15)][col=nt*16+(l>>4)*4+reg]
  if (row < N_NODES) {
    unsigned short* orow = ftb + (size_t)row * OUT_DIM;
    #pragma unroll
    for (int nt = 0; nt < 16; ++nt) {
      int col = nt * 16 + kgrp * 4;
      float4 bb = *(const float4*)(bias + col);
      f32x4 v = acc[nt];
      unsigned p0 = (unsigned)f2bf(v[0] + bb.x) | ((unsigned)f2bf(v[1] + bb.y) << 16);
      unsigned p1 = (unsigned)f2bf(v[2] + bb.z) | ((unsigned)f2bf(v[3] + bb.w) << 16);
      uint2 pv; pv.x = p0; pv.y = p1;
      *(uint2*)(orow + col) = pv;     // 8B packed store
    }
  }
}

// ---------------- K3: degree histogram --------------------------------------
__global__ void deg_count(const int* __restrict__ dst, int* __restrict__ deg) {
  int e = blockIdx.x * blockDim.x + threadIdx.x;
  if (e < N_EDGES) atomicAdd(&deg[dst[e]], 1);
}

// ---------------- K4: parallel exclusive scan (3 stages) --------------------
__global__ __launch_bounds__(1024) void scan_local(const int* __restrict__ deg,
                                                   int* __restrict__ off,
                                                   int* __restrict__ bsum) {
  __shared__ int buf[1024];
  int b = blockIdx.x, t = threadIdx.x, i = b * 1024 + t;
  int v = (i < N_NODES) ? deg[i] : 0;
  buf[t] = v;
  __syncthreads();
  for (int d = 1; d < 1024; d <<= 1) {
    int x = (t >= d) ? buf[t - d] : 0;
    __syncthreads();
    buf[t] += x;
    __syncthreads();
  }
  if (i < N_NODES) off[i] = buf[t] - v;     // exclusive (local)
  if (t == 1023) bsum[b] = buf[t];
}

__global__ void scan_bsums(const int* __restrict__ bsum, int* __restrict__ bscan,
                           int* __restrict__ offN) {
  int t = threadIdx.x;                      // 64 threads, 1 block
  int v = (t < NBLK_SCAN) ? bsum[t] : 0;
  int orig = v;
  for (int d = 1; d < 64; d <<= 1) {
    int x = __shfl_up(v, d);
    if (t >= d) v += x;
  }
  if (t < NBLK_SCAN) bscan[t] = v - orig;   // exclusive
  if (t == NBLK_SCAN - 1) offN[0] = v;      // total == N_EDGES
}

__global__ void add_bscan(int* __restrict__ off, const int* __restrict__ bscan) {
  int i = blockIdx.x * 256 + threadIdx.x;
  if (i < N_NODES) off[i] += bscan[i >> 10];
}

// ---------------- K5: scatter edges into CSR + edge score -------------------
__global__ void scatter_edges(const int* __restrict__ src, const int* __restrict__ dst,
                              const float* __restrict__ el, const float* __restrict__ er,
                              const int* __restrict__ off, int* __restrict__ cnt,
                              int* __restrict__ ssrc, float* __restrict__ se) {
  int e = blockIdx.x * blockDim.x + threadIdx.x;
  if (e >= N_EDGES) return;
  int s = src[e], d = dst[e];
  int pos = off[d] + atomicAdd(&cnt[d], 1);
  float ev = el[s] + er[d];
  ev = (ev > 0.f ? ev : 0.f) + 1.0f;
  ssrc[pos] = s;
  se[pos]   = ev;
}

// ---------------- K6: per-dst softmax + weighted aggregation ----------------
__global__ __launch_bounds__(256) void aggregate(const int* __restrict__ off,
                         const int* __restrict__ ssrc, const float* __restrict__ se,
                         const unsigned short* __restrict__ ftb,
                         float* __restrict__ out) {
  int wave = (int)((blockIdx.x * blockDim.x + threadIdx.x) >> 6);
  int lane = threadIdx.x & 63;
  if (wave >= N_NODES) return;
  int start = off[wave], end = off[wave + 1];
  float4 acc = make_float4(0.f, 0.f, 0.f, 0.f);
  if (end > start) {
    float m = -1e30f;
    for (int i = start + lane; i < end; i += 64) m = fmaxf(m, se[i]);
    #pragma unroll
    for (int o = 32; o > 0; o >>= 1) m = fmaxf(m, __shfl_xor(m, o));
    float dsum = 0.f;
    for (int i = start + lane; i < end; i += 64) dsum += __expf(se[i] - m);
    #pragma unroll
    for (int o = 32; o > 0; o >>= 1) dsum += __shfl_xor(dsum, o);
    float inv = 1.0f / dsum;
    for (int i = start; i < end; ++i) {        // uniform per-edge loop
      float w = __expf(se[i] - m) * inv;
      int s = ssrc[i];
      uint2 v = *(const uint2*)(ftb + (size_t)s * OUT_DIM + lane * 4);  // 4 bf16
      acc.x += w * bf2f((unsigned short)(v.x & 0xFFFF));
      acc.y += w * bf2f((unsigned short)(v.x >> 16));
      acc.z += w * bf2f((unsigned short)(v.y & 0xFFFF));
      acc.w += w * bf2f((unsigned short)(v.y >> 16));
    }
  }
  *(float4*)(out + (size_t)wave * OUT_DIM + lane * 4) = acc;
}

// ---------------- launch ----------------------------------------------------
extern "C" void kernel_launch(void* const* d_in, const int* in_sizes, int n_in,
                              void* d_out, int out_size, void* d_ws, size_t ws_size,
                              hipStream_t stream) {
  const float* feat = (const float*)d_in[0];
  // d_in[1] = p (unused in eval path)
  const float* Wl = (const float*)d_in[2];
  const float* bl = (const float*)d_in[3];
  const float* Wr = (const float*)d_in[4];
  const float* br = (const float*)d_in[5];
  const float* W  = (const float*)d_in[6];
  const float* b  = (const float*)d_in[7];
  const int* src  = (const int*)d_in[8];
  const int* dst  = (const int*)d_in[9];
  float* out = (float*)d_out;

  char* ws = (char*)d_ws;
  float* el = (float*)ws;            ws += (size_t)N_NODES * 4;
  float* er = (float*)ws;            ws += (size_t)N_NODES * 4;
  unsigned short* Wt  = (unsigned short*)ws;  ws += (size_t)OUT_DIM * IN_DIM * 2;
  unsigned short* ftb = (unsigned short*)ws;  ws += (size_t)N_NODES * OUT_DIM * 2;
  int* deg  = (int*)ws;              ws += (size_t)N_NODES * 4;
  int* cnt  = (int*)ws;              ws += (size_t)N_NODES * 4;
  int* off  = (int*)ws;              ws += (size_t)(N_NODES + 1) * 4;
  int* ssrc = (int*)ws;              ws += (size_t)N_EDGES * 4;
  float* se = (float*)ws;            ws += (size_t)N_EDGES * 4;
  int* bsum = (int*)ws;              ws += 64 * 4;
  int* bscan = (int*)ws;             ws += 64 * 4;

  hipMemsetAsync(deg, 0, (size_t)N_NODES * 4 * 2, stream);   // deg + cnt

  proj_lr<<<(N_NODES + 3) / 4, 256, 0, stream>>>(feat, Wl, bl, Wr, br, el, er);
  wconv<<<(OUT_DIM * IN_DIM) / 256, 256, 0, stream>>>(W, Wt);
  gemm_mfma<<<(N_NODES + GBM - 1) / GBM, 512, 0, stream>>>(feat, Wt, b, ftb);
  deg_count<<<(N_EDGES + 255) / 256, 256, 0, stream>>>(dst, deg);
  scan_local<<<NBLK_SCAN, 1024, 0, stream>>>(deg, off, bsum);
  scan_bsums<<<1, 64, 0, stream>>>(bsum, bscan, off + N_NODES);
  add_bscan<<<(N_NODES + 255) / 256, 256, 0, stream>>>(off, bscan);
  scatter_edges<<<(N_EDGES + 255) / 256, 256, 0, stream>>>(src, dst, el, er, off, cnt, ssrc, se);
  aggregate<<<(N_NODES + 3) / 4, 256, 0, stream>>>(off, ssrc, se, ftb, out);
}

// Round 6
// 230.115 us; speedup vs baseline: 2.3387x; 1.0715x over previous
//
#include <hip/hip_runtime.h>
#include <math.h>
#include <stdint.h>

#define N_NODES 50000
#define N_EDGES 800000
#define IN_DIM  512
#define OUT_DIM 256
#define NBLK_SCAN 49   // ceil(50000/1024)

typedef __attribute__((ext_vector_type(8))) short short8;
typedef __attribute__((ext_vector_type(4))) float f32x4;

__device__ inline unsigned short f2bf(float x) {
  unsigned u = __float_as_uint(x);
  unsigned r = (u + 0x7FFFu + ((u >> 16) & 1u)) >> 16;   // RNE
  return (unsigned short)r;
}
__device__ inline float bf2f(unsigned short h) {
  return __uint_as_float(((unsigned)h) << 16);
}

// ---------------- K1: W [512][256] fp32 -> Wt [256][512] bf16 ---------------
__global__ __launch_bounds__(256) void wconv(const float* __restrict__ W,
                                             unsigned short* __restrict__ Wt) {
  int i = blockIdx.x * 256 + threadIdx.x;   // over 131072
  int c = i >> 9, k = i & 511;
  Wt[i] = f2bf(W[(size_t)k * OUT_DIM + c]);
}

// ---------------- K2: ft = bf16(feat @ W + b) via MFMA, fused el/er ---------
// block: 512 threads = 8 waves; tile BM=128 rows x full N=256.
// Wave wm owns rows [m0+wm*16, +16). Each row is read by 4 lanes (kgrp=l>>4),
// so el/er partial dots are reduced with shfl_xor(16|32) at the end.
#define GBM 128
#define GBK 64
__global__ __launch_bounds__(512) void gemm_mfma(const float* __restrict__ feat,
                        const unsigned short* __restrict__ Wt,
                        const float* __restrict__ bias,
                        const float* __restrict__ Wl, const float* __restrict__ bl,
                        const float* __restrict__ Wr, const float* __restrict__ br,
                        unsigned short* __restrict__ ftb,
                        float* __restrict__ el, float* __restrict__ er) {
  __shared__ unsigned short Bs[OUT_DIM * GBK];   // 32 KB, XOR-swizzled rows of 128B
  const int tid  = threadIdx.x;
  const int lane = tid & 63;
  const int wm   = tid >> 6;          // 0..7
  const int m0   = blockIdx.x * GBM;

  f32x4 acc[16];
  #pragma unroll
  for (int nt = 0; nt < 16; ++nt) acc[nt] = (f32x4)0.f;

  int row  = m0 + wm * 16 + (lane & 15);
  int rowc = row < N_NODES ? row : N_NODES - 1;
  const float* fr = feat + (size_t)rowc * IN_DIM;
  const int kgrp = (lane >> 4);       // 0..3
  float al = 0.f, ar = 0.f;

  for (int k0 = 0; k0 < IN_DIM; k0 += GBK) {
    // stage Wt[0..255][k0..k0+64) into LDS (bf16, swizzled)
    #pragma unroll
    for (int i = tid; i < OUT_DIM * GBK / 8; i += 512) {   // 2048 x 16B chunks
      int c = i >> 3, o = i & 7;
      uint4 v = *(const uint4*)(Wt + (size_t)c * IN_DIM + k0 + o * 8);
      int boff = (c * 128 + o * 16) ^ ((c & 7) << 4);
      *(uint4*)((char*)Bs + boff) = v;
    }
    __syncthreads();

    #pragma unroll
    for (int kk = 0; kk < GBK; kk += 32) {
      // feat fragment: 8 consecutive fp32 -> bf16x8 (+ el/er partial dots)
      int kb = k0 + kk + kgrp * 8;
      float4 a0 = *(const float4*)(fr + kb);
      float4 a1 = *(const float4*)(fr + kb + 4);
      float4 wl0 = *(const float4*)(Wl + kb);
      float4 wl1 = *(const float4*)(Wl + kb + 4);
      float4 wr0 = *(const float4*)(Wr + kb);
      float4 wr1 = *(const float4*)(Wr + kb + 4);
      al += a0.x*wl0.x + a0.y*wl0.y + a0.z*wl0.z + a0.w*wl0.w
          + a1.x*wl1.x + a1.y*wl1.y + a1.z*wl1.z + a1.w*wl1.w;
      ar += a0.x*wr0.x + a0.y*wr0.y + a0.z*wr0.z + a0.w*wr0.w
          + a1.x*wr1.x + a1.y*wr1.y + a1.z*wr1.z + a1.w*wr1.w;
      short8 yf;
      yf[0] = (short)f2bf(a0.x); yf[1] = (short)f2bf(a0.y);
      yf[2] = (short)f2bf(a0.z); yf[3] = (short)f2bf(a0.w);
      yf[4] = (short)f2bf(a1.x); yf[5] = (short)f2bf(a1.y);
      yf[6] = (short)f2bf(a1.z); yf[7] = (short)f2bf(a1.w);
      int kloc = kk * 2 + kgrp * 16;    // byte offset inside 128B row
      #pragma unroll
      for (int nt = 0; nt < 16; ++nt) {
        int c = nt * 16 + (lane & 15);
        int boff = (c * 128 + kloc) ^ ((c & 7) << 4);
        short8 xf = *(const short8*)((const char*)Bs + boff);
        acc[nt] = __builtin_amdgcn_mfma_f32_16x16x32_bf16(xf, yf, acc[nt], 0, 0, 0);
      }
    }
    __syncthreads();
  }

  // el/er: reduce the 4 kgrp partials of each row
  al += __shfl_xor(al, 16); al += __shfl_xor(al, 32);
  ar += __shfl_xor(ar, 16); ar += __shfl_xor(ar, 32);
  if (kgrp == 0 && row < N_NODES) {
    el[row] = al + bl[0];
    er[row] = ar + br[0];
  }

  // store: acc[nt][reg] = ft[row=m0+wm*16+(l&15)][col=nt*16+(l>>4)*4+reg]
  if (row < N_NODES) {
    unsigned short* orow = ftb + (size_t)row * OUT_DIM;
    #pragma unroll
    for (int nt = 0; nt < 16; ++nt) {
      int col = nt * 16 + kgrp * 4;
      float4 bb = *(const float4*)(bias + col);
      f32x4 v = acc[nt];
      unsigned p0 = (unsigned)f2bf(v[0] + bb.x) | ((unsigned)f2bf(v[1] + bb.y) << 16);
      unsigned p1 = (unsigned)f2bf(v[2] + bb.z) | ((unsigned)f2bf(v[3] + bb.w) << 16);
      uint2 pv; pv.x = p0; pv.y = p1;
      *(uint2*)(orow + col) = pv;     // 8B packed store
    }
  }
}

// ---------------- K3: degree histogram --------------------------------------
__global__ void deg_count(const int* __restrict__ dst, int* __restrict__ deg) {
  int e = blockIdx.x * blockDim.x + threadIdx.x;
  if (e < N_EDGES) atomicAdd(&deg[dst[e]], 1);
}

// ---------------- K4: parallel exclusive scan (3 stages) --------------------
__global__ __launch_bounds__(1024) void scan_local(const int* __restrict__ deg,
                                                   int* __restrict__ off,
                                                   int* __restrict__ bsum) {
  __shared__ int buf[1024];
  int b = blockIdx.x, t = threadIdx.x, i = b * 1024 + t;
  int v = (i < N_NODES) ? deg[i] : 0;
  buf[t] = v;
  __syncthreads();
  for (int d = 1; d < 1024; d <<= 1) {
    int x = (t >= d) ? buf[t - d] : 0;
    __syncthreads();
    buf[t] += x;
    __syncthreads();
  }
  if (i < N_NODES) off[i] = buf[t] - v;     // exclusive (local)
  if (t == 1023) bsum[b] = buf[t];
}

__global__ void scan_bsums(const int* __restrict__ bsum, int* __restrict__ bscan,
                           int* __restrict__ offN) {
  int t = threadIdx.x;                      // 64 threads, 1 block
  int v = (t < NBLK_SCAN) ? bsum[t] : 0;
  int orig = v;
  for (int d = 1; d < 64; d <<= 1) {
    int x = __shfl_up(v, d);
    if (t >= d) v += x;
  }
  if (t < NBLK_SCAN) bscan[t] = v - orig;   // exclusive
  if (t == NBLK_SCAN - 1) offN[0] = v;      // total == N_EDGES
}

__global__ void add_bscan(int* __restrict__ off, const int* __restrict__ bscan) {
  int i = blockIdx.x * 256 + threadIdx.x;
  if (i < N_NODES) off[i] += bscan[i >> 10];
}

// ---------------- K5: scatter edges into CSR + edge score (int2 packed) -----
__global__ void scatter_edges(const int* __restrict__ src, const int* __restrict__ dst,
                              const float* __restrict__ el, const float* __restrict__ er,
                              const int* __restrict__ off, int* __restrict__ cnt,
                              int2* __restrict__ sed) {
  int e = blockIdx.x * blockDim.x + threadIdx.x;
  if (e >= N_EDGES) return;
  int s = src[e], d = dst[e];
  int pos = off[d] + atomicAdd(&cnt[d], 1);
  float ev = el[s] + er[d];
  ev = (ev > 0.f ? ev : 0.f) + 1.0f;
  int2 pv; pv.x = s; pv.y = __float_as_int(ev);
  sed[pos] = pv;
}

// ---------------- K6: fused single-pass softmax + aggregation ---------------
// No max-shift: scores = relu(el+er)+1 are O(10); exp() is safe in fp32 and
// normalization cancels the shift exactly. One pass: w=exp(s); dsum+=w;
// acc+=w*ft[src]; finally acc/dsum. Unroll x4 -> 4 outstanding gathers.
__global__ __launch_bounds__(256) void aggregate(const int* __restrict__ off,
                         const int2* __restrict__ sed,
                         const unsigned short* __restrict__ ftb,
                         float* __restrict__ out) {
  int node = (int)((blockIdx.x * blockDim.x + threadIdx.x) >> 6);
  int lane = threadIdx.x & 63;
  if (node >= N_NODES) return;
  int start = off[node], end = off[node + 1];

  f32x4 a0 = (f32x4)0.f, a1 = (f32x4)0.f, a2 = (f32x4)0.f, a3 = (f32x4)0.f;
  float d0 = 0.f, d1 = 0.f, d2 = 0.f, d3 = 0.f;

  int i = start;
  for (; i + 4 <= end; i += 4) {
    int2 e0 = sed[i], e1 = sed[i + 1], e2 = sed[i + 2], e3 = sed[i + 3];
    uint2 v0 = *((const uint2*)(ftb + (size_t)e0.x * OUT_DIM) + lane);
    uint2 v1 = *((const uint2*)(ftb + (size_t)e1.x * OUT_DIM) + lane);
    uint2 v2 = *((const uint2*)(ftb + (size_t)e2.x * OUT_DIM) + lane);
    uint2 v3 = *((const uint2*)(ftb + (size_t)e3.x * OUT_DIM) + lane);
    float w0 = __expf(__int_as_float(e0.y));
    float w1 = __expf(__int_as_float(e1.y));
    float w2 = __expf(__int_as_float(e2.y));
    float w3 = __expf(__int_as_float(e3.y));
    d0 += w0; d1 += w1; d2 += w2; d3 += w3;
    a0[0] += w0 * bf2f((unsigned short)(v0.x & 0xFFFF));
    a0[1] += w0 * bf2f((unsigned short)(v0.x >> 16));
    a0[2] += w0 * bf2f((unsigned short)(v0.y & 0xFFFF));
    a0[3] += w0 * bf2f((unsigned short)(v0.y >> 16));
    a1[0] += w1 * bf2f((unsigned short)(v1.x & 0xFFFF));
    a1[1] += w1 * bf2f((unsigned short)(v1.x >> 16));
    a1[2] += w1 * bf2f((unsigned short)(v1.y & 0xFFFF));
    a1[3] += w1 * bf2f((unsigned short)(v1.y >> 16));
    a2[0] += w2 * bf2f((unsigned short)(v2.x & 0xFFFF));
    a2[1] += w2 * bf2f((unsigned short)(v2.x >> 16));
    a2[2] += w2 * bf2f((unsigned short)(v2.y & 0xFFFF));
    a2[3] += w2 * bf2f((unsigned short)(v2.y >> 16));
    a3[0] += w3 * bf2f((unsigned short)(v3.x & 0xFFFF));
    a3[1] += w3 * bf2f((unsigned short)(v3.x >> 16));
    a3[2] += w3 * bf2f((unsigned short)(v3.y & 0xFFFF));
    a3[3] += w3 * bf2f((unsigned short)(v3.y >> 16));
  }
  for (; i < end; ++i) {
    int2 e0 = sed[i];
    uint2 v0 = *((const uint2*)(ftb + (size_t)e0.x * OUT_DIM) + lane);
    float w0 = __expf(__int_as_float(e0.y));
    d0 += w0;
    a0[0] += w0 * bf2f((unsigned short)(v0.x & 0xFFFF));
    a0[1] += w0 * bf2f((unsigned short)(v0.x >> 16));
    a0[2] += w0 * bf2f((unsigned short)(v0.y & 0xFFFF));
    a0[3] += w0 * bf2f((unsigned short)(v0.y >> 16));
  }

  f32x4 acc = (a0 + a1) + (a2 + a3);
  float dsum = (d0 + d1) + (d2 + d3);
  float inv = (end > start) ? 1.0f / dsum : 0.f;
  acc *= inv;
  __builtin_nontemporal_store(acc, (f32x4*)(out + (size_t)node * OUT_DIM + lane * 4));
}

// ---------------- launch ----------------------------------------------------
extern "C" void kernel_launch(void* const* d_in, const int* in_sizes, int n_in,
                              void* d_out, int out_size, void* d_ws, size_t ws_size,
                              hipStream_t stream) {
  const float* feat = (const float*)d_in[0];
  // d_in[1] = p (unused in eval path)
  const float* Wl = (const float*)d_in[2];
  const float* bl = (const float*)d_in[3];
  const float* Wr = (const float*)d_in[4];
  const float* br = (const float*)d_in[5];
  const float* W  = (const float*)d_in[6];
  const float* b  = (const float*)d_in[7];
  const int* src  = (const int*)d_in[8];
  const int* dst  = (const int*)d_in[9];
  float* out = (float*)d_out;

  char* ws = (char*)d_ws;
  float* el = (float*)ws;            ws += (size_t)N_NODES * 4;
  float* er = (float*)ws;            ws += (size_t)N_NODES * 4;
  unsigned short* Wt  = (unsigned short*)ws;  ws += (size_t)OUT_DIM * IN_DIM * 2;
  unsigned short* ftb = (unsigned short*)ws;  ws += (size_t)N_NODES * OUT_DIM * 2;
  int* deg  = (int*)ws;              ws += (size_t)N_NODES * 4;
  int* cnt  = (int*)ws;              ws += (size_t)N_NODES * 4;
  int* off  = (int*)ws;              ws += (size_t)(N_NODES + 1) * 4;
  int2* sed = (int2*)ws;             ws += (size_t)N_EDGES * 8;
  int* bsum = (int*)ws;              ws += 64 * 4;
  int* bscan = (int*)ws;             ws += 64 * 4;

  hipMemsetAsync(deg, 0, (size_t)N_NODES * 4 * 2, stream);   // deg + cnt

  wconv<<<(OUT_DIM * IN_DIM) / 256, 256, 0, stream>>>(W, Wt);
  gemm_mfma<<<(N_NODES + GBM - 1) / GBM, 512, 0, stream>>>(feat, Wt, b, Wl, bl, Wr, br,
                                                           ftb, el, er);
  deg_count<<<(N_EDGES + 255) / 256, 256, 0, stream>>>(dst, deg);
  scan_local<<<NBLK_SCAN, 1024, 0, stream>>>(deg, off, bsum);
  scan_bsums<<<1, 64, 0, stream>>>(bsum, bscan, off + N_NODES);
  add_bscan<<<(N_NODES + 255) / 256, 256, 0, stream>>>(off, bscan);
  scatter_edges<<<(N_EDGES + 255) / 256, 256, 0, stream>>>(src, dst, el, er, off, cnt, sed);
  aggregate<<<(N_NODES + 3) / 4, 256, 0, stream>>>(off, sed, ftb, out);
}

// Round 7
// 213.771 us; speedup vs baseline: 2.5175x; 1.0765x over previous
//
#include <hip/hip_runtime.h>
#include <math.h>
#include <stdint.h>

#define N_NODES 50000
#define N_EDGES 800000
#define IN_DIM  512
#define OUT_DIM 256
#define NBLK_SCAN 49   // ceil(50000/1024)

typedef __attribute__((ext_vector_type(8))) short short8;
typedef __attribute__((ext_vector_type(4))) float f32x4;

__device__ inline unsigned short f2bf(float x) {
  unsigned u = __float_as_uint(x);
  unsigned r = (u + 0x7FFFu + ((u >> 16) & 1u)) >> 16;   // RNE
  return (unsigned short)r;
}
__device__ inline float bf2f(unsigned short h) {
  return __uint_as_float(((unsigned)h) << 16);
}

// async 16B global->LDS copy (lds dest must be wave-uniform base; HW adds lane*16)
__device__ inline void gload_lds16(const void* g, void* l) {
  __builtin_amdgcn_global_load_lds(
      (const __attribute__((address_space(1))) unsigned int*)g,
      (__attribute__((address_space(3))) unsigned int*)l, 16, 0, 0);
}

// ---------------- K1: W [512][256] fp32 -> Wtp (pre-swizzled LDS image) -----
// Wtp is 8 chunks (one per K-step of 64) of 16384 bf16 = 32 KB each.
// Within a chunk: byte offset = (c*128 + o*16) ^ ((c&7)<<4), o=(k>>3)&7,
// element within 16B group = k&7.  Staging in gemm is then a linear copy.
__global__ __launch_bounds__(256) void wconv(const float* __restrict__ W,
                                             unsigned short* __restrict__ Wtp) {
  int i = blockIdx.x * 256 + threadIdx.x;   // over 131072
  int c = i >> 9, k = i & 511;
  int kc = k >> 6;
  int o  = (k >> 3) & 7;
  int boff = (c * 128 + o * 16) ^ ((c & 7) << 4);
  int elem = kc * 16384 + (boff >> 1) + (k & 7);
  Wtp[elem] = f2bf(W[(size_t)k * OUT_DIM + c]);
}

// ---------------- K2: ft = bf16(feat @ W + b) via MFMA, fused el/er ---------
// block: 256 threads = 4 waves; tile BM=64 rows x full N=256.
// Wave wv owns rows [m0+wv*16, +16), all 256 cols (16 n-tiles of 16).
// Staging: async global_load_lds of the pre-swizzled 32 KB chunk (linear).
#define GBM 64
#define GBK 64
__global__ __launch_bounds__(256) void gemm_mfma(const float* __restrict__ feat,
                        const unsigned short* __restrict__ Wtp,
                        const float* __restrict__ bias,
                        const float* __restrict__ Wl, const float* __restrict__ bl,
                        const float* __restrict__ Wr, const float* __restrict__ br,
                        unsigned short* __restrict__ ftb,
                        float* __restrict__ el, float* __restrict__ er) {
  __shared__ unsigned short Bs[OUT_DIM * GBK];   // 32 KB
  const int tid  = threadIdx.x;
  const int lane = tid & 63;
  const int wv   = tid >> 6;          // 0..3
  const int m0   = blockIdx.x * GBM;

  f32x4 acc[16];
  #pragma unroll
  for (int nt = 0; nt < 16; ++nt) acc[nt] = (f32x4)0.f;

  int row  = m0 + wv * 16 + (lane & 15);
  int rowc = row < N_NODES ? row : N_NODES - 1;
  const float* fr = feat + (size_t)rowc * IN_DIM;
  const int kgrp = (lane >> 4);       // 0..3
  float al = 0.f, ar = 0.f;

  for (int kc = 0; kc < IN_DIM / GBK; ++kc) {
    // linear async stage of pre-swizzled chunk: 32 segs of 1 KB
    const char* gsrc = (const char*)Wtp + (size_t)kc * 32768;
    #pragma unroll
    for (int j = 0; j < 8; ++j) {
      int seg = j * 4 + wv;                       // wave-uniform
      gload_lds16(gsrc + seg * 1024 + (lane << 4), (char*)Bs + seg * 1024);
    }
    __syncthreads();   // compiler drains vmcnt before barrier

    #pragma unroll
    for (int kk = 0; kk < GBK; kk += 32) {
      // feat fragment: 8 consecutive fp32 -> bf16x8 (+ el/er partial dots)
      int kb = kc * GBK + kk + kgrp * 8;
      float4 a0 = *(const float4*)(fr + kb);
      float4 a1 = *(const float4*)(fr + kb + 4);
      float4 wl0 = *(const float4*)(Wl + kb);
      float4 wl1 = *(const float4*)(Wl + kb + 4);
      float4 wr0 = *(const float4*)(Wr + kb);
      float4 wr1 = *(const float4*)(Wr + kb + 4);
      al += a0.x*wl0.x + a0.y*wl0.y + a0.z*wl0.z + a0.w*wl0.w
          + a1.x*wl1.x + a1.y*wl1.y + a1.z*wl1.z + a1.w*wl1.w;
      ar += a0.x*wr0.x + a0.y*wr0.y + a0.z*wr0.z + a0.w*wr0.w
          + a1.x*wr1.x + a1.y*wr1.y + a1.z*wr1.z + a1.w*wr1.w;
      short8 yf;
      yf[0] = (short)f2bf(a0.x); yf[1] = (short)f2bf(a0.y);
      yf[2] = (short)f2bf(a0.z); yf[3] = (short)f2bf(a0.w);
      yf[4] = (short)f2bf(a1.x); yf[5] = (short)f2bf(a1.y);
      yf[6] = (short)f2bf(a1.z); yf[7] = (short)f2bf(a1.w);
      int kloc = kk * 2 + kgrp * 16;    // byte offset inside 128B row
      #pragma unroll
      for (int nt = 0; nt < 16; ++nt) {
        int c = nt * 16 + (lane & 15);
        int boff = (c * 128 + kloc) ^ ((c & 7) << 4);
        short8 xf = *(const short8*)((const char*)Bs + boff);
        acc[nt] = __builtin_amdgcn_mfma_f32_16x16x32_bf16(xf, yf, acc[nt], 0, 0, 0);
      }
    }
    __syncthreads();
  }

  // el/er: reduce the 4 kgrp partials of each row
  al += __shfl_xor(al, 16); al += __shfl_xor(al, 32);
  ar += __shfl_xor(ar, 16); ar += __shfl_xor(ar, 32);
  if (kgrp == 0 && row < N_NODES) {
    el[row] = al + bl[0];
    er[row] = ar + br[0];
  }

  // store: acc[nt][reg] = ft[row=m0+wv*16+(l&15)][col=nt*16+(l>>4)*4+reg]
  if (row < N_NODES) {
    unsigned short* orow = ftb + (size_t)row * OUT_DIM;
    #pragma unroll
    for (int nt = 0; nt < 16; ++nt) {
      int col = nt * 16 + kgrp * 4;
      float4 bb = *(const float4*)(bias + col);
      f32x4 v = acc[nt];
      unsigned p0 = (unsigned)f2bf(v[0] + bb.x) | ((unsigned)f2bf(v[1] + bb.y) << 16);
      unsigned p1 = (unsigned)f2bf(v[2] + bb.z) | ((unsigned)f2bf(v[3] + bb.w) << 16);
      uint2 pv; pv.x = p0; pv.y = p1;
      *(uint2*)(orow + col) = pv;     // 8B packed store
    }
  }
}

// ---------------- K3: degree histogram --------------------------------------
__global__ void deg_count(const int* __restrict__ dst, int* __restrict__ deg) {
  int e = blockIdx.x * blockDim.x + threadIdx.x;
  if (e < N_EDGES) atomicAdd(&deg[dst[e]], 1);
}

// ---------------- K4: parallel exclusive scan (3 stages) --------------------
__global__ __launch_bounds__(1024) void scan_local(const int* __restrict__ deg,
                                                   int* __restrict__ off,
                                                   int* __restrict__ bsum) {
  __shared__ int buf[1024];
  int b = blockIdx.x, t = threadIdx.x, i = b * 1024 + t;
  int v = (i < N_NODES) ? deg[i] : 0;
  buf[t] = v;
  __syncthreads();
  for (int d = 1; d < 1024; d <<= 1) {
    int x = (t >= d) ? buf[t - d] : 0;
    __syncthreads();
    buf[t] += x;
    __syncthreads();
  }
  if (i < N_NODES) off[i] = buf[t] - v;     // exclusive (local)
  if (t == 1023) bsum[b] = buf[t];
}

__global__ void scan_bsums(const int* __restrict__ bsum, int* __restrict__ bscan,
                           int* __restrict__ offN) {
  int t = threadIdx.x;                      // 64 threads, 1 block
  int v = (t < NBLK_SCAN) ? bsum[t] : 0;
  int orig = v;
  for (int d = 1; d < 64; d <<= 1) {
    int x = __shfl_up(v, d);
    if (t >= d) v += x;
  }
  if (t < NBLK_SCAN) bscan[t] = v - orig;   // exclusive
  if (t == NBLK_SCAN - 1) offN[0] = v;      // total == N_EDGES
}

__global__ void add_bscan(int* __restrict__ off, const int* __restrict__ bscan) {
  int i = blockIdx.x * 256 + threadIdx.x;
  if (i < N_NODES) off[i] += bscan[i >> 10];
}

// ---------------- K5: scatter edges into CSR + edge score (int2 packed) -----
__global__ void scatter_edges(const int* __restrict__ src, const int* __restrict__ dst,
                              const float* __restrict__ el, const float* __restrict__ er,
                              const int* __restrict__ off, int* __restrict__ cnt,
                              int2* __restrict__ sed) {
  int e = blockIdx.x * blockDim.x + threadIdx.x;
  if (e >= N_EDGES) return;
  int s = src[e], d = dst[e];
  int pos = off[d] + atomicAdd(&cnt[d], 1);
  float ev = el[s] + er[d];
  ev = (ev > 0.f ? ev : 0.f) + 1.0f;
  int2 pv; pv.x = s; pv.y = __float_as_int(ev);
  sed[pos] = pv;
}

// ---------------- K6: fused single-pass softmax + aggregation ---------------
// No max-shift: scores = relu(el+er)+1 are O(10); exp() safe in fp32 and
// normalization cancels the shift exactly. Unroll x4 -> 4 outstanding gathers.
__global__ __launch_bounds__(256) void aggregate(const int* __restrict__ off,
                         const int2* __restrict__ sed,
                         const unsigned short* __restrict__ ftb,
                         float* __restrict__ out) {
  int node = (int)((blockIdx.x * blockDim.x + threadIdx.x) >> 6);
  int lane = threadIdx.x & 63;
  if (node >= N_NODES) return;
  int start = off[node], end = off[node + 1];

  f32x4 a0 = (f32x4)0.f, a1 = (f32x4)0.f, a2 = (f32x4)0.f, a3 = (f32x4)0.f;
  float d0 = 0.f, d1 = 0.f, d2 = 0.f, d3 = 0.f;

  int i = start;
  for (; i + 4 <= end; i += 4) {
    int2 e0 = sed[i], e1 = sed[i + 1], e2 = sed[i + 2], e3 = sed[i + 3];
    uint2 v0 = *((const uint2*)(ftb + (size_t)e0.x * OUT_DIM) + lane);
    uint2 v1 = *((const uint2*)(ftb + (size_t)e1.x * OUT_DIM) + lane);
    uint2 v2 = *((const uint2*)(ftb + (size_t)e2.x * OUT_DIM) + lane);
    uint2 v3 = *((const uint2*)(ftb + (size_t)e3.x * OUT_DIM) + lane);
    float w0 = __expf(__int_as_float(e0.y));
    float w1 = __expf(__int_as_float(e1.y));
    float w2 = __expf(__int_as_float(e2.y));
    float w3 = __expf(__int_as_float(e3.y));
    d0 += w0; d1 += w1; d2 += w2; d3 += w3;
    a0[0] += w0 * bf2f((unsigned short)(v0.x & 0xFFFF));
    a0[1] += w0 * bf2f((unsigned short)(v0.x >> 16));
    a0[2] += w0 * bf2f((unsigned short)(v0.y & 0xFFFF));
    a0[3] += w0 * bf2f((unsigned short)(v0.y >> 16));
    a1[0] += w1 * bf2f((unsigned short)(v1.x & 0xFFFF));
    a1[1] += w1 * bf2f((unsigned short)(v1.x >> 16));
    a1[2] += w1 * bf2f((unsigned short)(v1.y & 0xFFFF));
    a1[3] += w1 * bf2f((unsigned short)(v1.y >> 16));
    a2[0] += w2 * bf2f((unsigned short)(v2.x & 0xFFFF));
    a2[1] += w2 * bf2f((unsigned short)(v2.x >> 16));
    a2[2] += w2 * bf2f((unsigned short)(v2.y & 0xFFFF));
    a2[3] += w2 * bf2f((unsigned short)(v2.y >> 16));
    a3[0] += w3 * bf2f((unsigned short)(v3.x & 0xFFFF));
    a3[1] += w3 * bf2f((unsigned short)(v3.x >> 16));
    a3[2] += w3 * bf2f((unsigned short)(v3.y & 0xFFFF));
    a3[3] += w3 * bf2f((unsigned short)(v3.y >> 16));
  }
  for (; i < end; ++i) {
    int2 e0 = sed[i];
    uint2 v0 = *((const uint2*)(ftb + (size_t)e0.x * OUT_DIM) + lane);
    float w0 = __expf(__int_as_float(e0.y));
    d0 += w0;
    a0[0] += w0 * bf2f((unsigned short)(v0.x & 0xFFFF));
    a0[1] += w0 * bf2f((unsigned short)(v0.x >> 16));
    a0[2] += w0 * bf2f((unsigned short)(v0.y & 0xFFFF));
    a0[3] += w0 * bf2f((unsigned short)(v0.y >> 16));
  }

  f32x4 acc = (a0 + a1) + (a2 + a3);
  float dsum = (d0 + d1) + (d2 + d3);
  float inv = (end > start) ? 1.0f / dsum : 0.f;
  acc *= inv;
  __builtin_nontemporal_store(acc, (f32x4*)(out + (size_t)node * OUT_DIM + lane * 4));
}

// ---------------- launch ----------------------------------------------------
extern "C" void kernel_launch(void* const* d_in, const int* in_sizes, int n_in,
                              void* d_out, int out_size, void* d_ws, size_t ws_size,
                              hipStream_t stream) {
  const float* feat = (const float*)d_in[0];
  // d_in[1] = p (unused in eval path)
  const float* Wl = (const float*)d_in[2];
  const float* bl = (const float*)d_in[3];
  const float* Wr = (const float*)d_in[4];
  const float* br = (const float*)d_in[5];
  const float* W  = (const float*)d_in[6];
  const float* b  = (const float*)d_in[7];
  const int* src  = (const int*)d_in[8];
  const int* dst  = (const int*)d_in[9];
  float* out = (float*)d_out;

  char* ws = (char*)d_ws;
  float* el = (float*)ws;            ws += (size_t)N_NODES * 4;
  float* er = (float*)ws;            ws += (size_t)N_NODES * 4;
  unsigned short* Wtp = (unsigned short*)ws;  ws += (size_t)OUT_DIM * IN_DIM * 2;
  unsigned short* ftb = (unsigned short*)ws;  ws += (size_t)N_NODES * OUT_DIM * 2;
  int* deg  = (int*)ws;              ws += (size_t)N_NODES * 4;
  int* cnt  = (int*)ws;              ws += (size_t)N_NODES * 4;
  int* off  = (int*)ws;              ws += (size_t)(N_NODES + 1) * 4;
  int2* sed = (int2*)ws;             ws += (size_t)N_EDGES * 8;
  int* bsum = (int*)ws;              ws += 64 * 4;
  int* bscan = (int*)ws;             ws += 64 * 4;

  hipMemsetAsync(deg, 0, (size_t)N_NODES * 4 * 2, stream);   // deg + cnt

  wconv<<<(OUT_DIM * IN_DIM) / 256, 256, 0, stream>>>(W, Wtp);
  gemm_mfma<<<(N_NODES + GBM - 1) / GBM, 256, 0, stream>>>(feat, Wtp, b, Wl, bl, Wr, br,
                                                           ftb, el, er);
  deg_count<<<(N_EDGES + 255) / 256, 256, 0, stream>>>(dst, deg);
  scan_local<<<NBLK_SCAN, 1024, 0, stream>>>(deg, off, bsum);
  scan_bsums<<<1, 64, 0, stream>>>(bsum, bscan, off + N_NODES);
  add_bscan<<<(N_NODES + 255) / 256, 256, 0, stream>>>(off, bscan);
  scatter_edges<<<(N_EDGES + 255) / 256, 256, 0, stream>>>(src, dst, el, er, off, cnt, sed);
  aggregate<<<(N_NODES + 3) / 4, 256, 0, stream>>>(off, sed, ftb, out);
}

// Round 9
// 201.682 us; speedup vs baseline: 2.6684x; 1.0599x over previous
//
#include <hip/hip_runtime.h>
#include <math.h>
#include <stdint.h>

#define N_NODES 50000
#define N_EDGES 800000
#define IN_DIM  512
#define OUT_DIM 256
#define NBLK_SCAN 49   // ceil(50000/1024)

typedef __attribute__((ext_vector_type(8))) short short8;
typedef __attribute__((ext_vector_type(4))) float f32x4;

__device__ inline unsigned f2bf(float x) {
  unsigned u = __float_as_uint(x);
  return (u + 0x7FFFu + ((u >> 16) & 1u)) >> 16;   // RNE
}
__device__ inline float bf2f(unsigned short h) {
  return __uint_as_float(((unsigned)h) << 16);
}

// ---------------- K1: W [512][256] -> Wtp frag-major bf16 -------------------
// Frag layout: for col-tile nt(0..15), k-step kk(0..15), lane(0..63), j(0..7):
//   Wtp[((nt*16+kk)*64 + lane)*8 + j] = bf16( W[k][c] )
//   with k = kk*32 + (lane>>4)*8 + j, c = nt*16 + (lane&15)
// gemm then loads per-lane 16B chunks, lane-consecutive -> fully coalesced.
__global__ __launch_bounds__(256) void wconv(const float* __restrict__ W,
                                             unsigned short* __restrict__ Wtp) {
  int i = blockIdx.x * 256 + threadIdx.x;   // over 131072
  int c = i & 255, k = i >> 8;              // coalesced read over c
  int nt = c >> 4, kk = k >> 5;
  int lane = (((k & 31) >> 3) << 4) | (c & 15);
  int j = k & 7;
  Wtp[(((size_t)(nt * 16 + kk)) * 64 + lane) * 8 + j] =
      (unsigned short)f2bf(W[(size_t)k * OUT_DIM + c]);
}

// ---------------- K2: ft = bf16(feat @ W + b), W-in-regs, feat-in-LDS -------
// block: 512 thr = 8 waves; tile = 128 rows x 256 cols, full K in one pass.
// Wave wv owns cols [wv*32, wv*32+32) (nt = 2wv, 2wv+1); W-frags in 128 VGPRs.
// LDS: feat tile 128 rows x 512 k bf16 = 128 KB (dynamic), frag-major:
//   byte = ((mg*16+kk)*64 + slot)*16 + (k&7)*2,  slot = lane_idx ^ (kk&7)
//   where lane_idx = ((k>>3)&3)*16 + (row&15), mg = row>>4.
// Write: 4 accesses/bank (= b64 structural min). Read: consecutive 16B, clean.
#define GBM 128
__global__ __launch_bounds__(512, 2) void gemm_mfma(const float* __restrict__ feat,
                        const unsigned short* __restrict__ Wtp,
                        const float* __restrict__ bias,
                        const float* __restrict__ Wl, const float* __restrict__ bl,
                        const float* __restrict__ Wr, const float* __restrict__ br,
                        unsigned short* __restrict__ ftb,
                        float* __restrict__ el, float* __restrict__ er) {
  extern __shared__ char smem[];
  const int tid  = threadIdx.x;
  const int lane = tid & 63;
  const int wv   = tid >> 6;          // 0..7
  const int m0   = blockIdx.x * GBM;

  // ---- W-frags: issue early, consumed after the barrier ----
  short8 wf[2][16];
  #pragma unroll
  for (int t = 0; t < 2; ++t) {
    #pragma unroll
    for (int kk = 0; kk < 16; ++kk) {
      int nt = wv * 2 + t;
      wf[t][kk] = *(const short8*)(Wtp + (((size_t)(nt * 16 + kk)) * 64 + lane) * 8);
    }
  }

  // ---- stage: wave wv stages rows [wv*16, wv*16+16), 1KB-contig per instr ----
  const float4* wl4 = (const float4*)Wl;
  const float4* wr4 = (const float4*)Wr;
  for (int rr = 0; rr < 16; ++rr) {
    int r = wv * 16 + rr;
    int grow = m0 + r;
    int gc = grow < N_NODES ? grow : N_NODES - 1;
    const float4* frow = (const float4*)(feat + (size_t)gc * IN_DIM);
    float elp = 0.f, erp = 0.f;
    #pragma unroll
    for (int half = 0; half < 2; ++half) {
      int k4 = half * 64 + lane;          // float4 index 0..127
      float4 f  = frow[k4];
      float4 wl = wl4[k4];
      float4 wr = wr4[k4];
      elp += f.x * wl.x + f.y * wl.y + f.z * wl.z + f.w * wl.w;
      erp += f.x * wr.x + f.y * wr.y + f.z * wr.z + f.w * wr.w;
      uint2 pv;
      pv.x = f2bf(f.x) | (f2bf(f.y) << 16);
      pv.y = f2bf(f.z) | (f2bf(f.w) << 16);
      int kk   = half * 8 + (lane >> 3);
      int slot = ((((lane >> 1) & 3) << 4) | (r & 15)) ^ (lane >> 3);
      int boff = ((((r >> 4) * 16 + kk) * 64) + slot) * 16 + (lane & 1) * 8;
      *(uint2*)(smem + boff) = pv;
    }
    #pragma unroll
    for (int o = 32; o > 0; o >>= 1) {
      elp += __shfl_xor(elp, o);
      erp += __shfl_xor(erp, o);
    }
    if (lane == 0 && grow < N_NODES) {
      el[grow] = elp + bl[0];
      er[grow] = erp + br[0];
    }
  }
  __syncthreads();

  // ---- compute: pure LDS + MFMA ----
  f32x4 acc[8][2];
  #pragma unroll
  for (int mg = 0; mg < 8; ++mg) {
    acc[mg][0] = (f32x4)0.f;
    acc[mg][1] = (f32x4)0.f;
  }
  #pragma unroll
  for (int kk = 0; kk < 16; ++kk) {
    #pragma unroll
    for (int mg = 0; mg < 8; ++mg) {
      short8 fa = *(const short8*)(smem + (((mg * 16 + kk) * 64) + (lane ^ (kk & 7))) * 16);
      acc[mg][0] = __builtin_amdgcn_mfma_f32_16x16x32_bf16(wf[0][kk], fa, acc[mg][0], 0, 0, 0);
      acc[mg][1] = __builtin_amdgcn_mfma_f32_16x16x32_bf16(wf[1][kk], fa, acc[mg][1], 0, 0, 0);
    }
  }

  // ---- store: row = m0+mg*16+(l&15), col = nt*16 + (l>>4)*4 + reg ----
  #pragma unroll
  for (int mg = 0; mg < 8; ++mg) {
    int row = m0 + mg * 16 + (lane & 15);
    if (row < N_NODES) {
      unsigned short* orow = ftb + (size_t)row * OUT_DIM;
      #pragma unroll
      for (int t = 0; t < 2; ++t) {
        int col = (wv * 2 + t) * 16 + (lane >> 4) * 4;
        float4 bb = *(const float4*)(bias + col);
        f32x4 v = acc[mg][t];
        uint2 pv;
        pv.x = f2bf(v[0] + bb.x) | (f2bf(v[1] + bb.y) << 16);
        pv.y = f2bf(v[2] + bb.z) | (f2bf(v[3] + bb.w) << 16);
        *(uint2*)(orow + col) = pv;
      }
    }
  }
}

// ---------------- K3: degree histogram --------------------------------------
__global__ void deg_count(const int* __restrict__ dst, int* __restrict__ deg) {
  int e = blockIdx.x * blockDim.x + threadIdx.x;
  if (e < N_EDGES) atomicAdd(&deg[dst[e]], 1);
}

// ---------------- K4: parallel exclusive scan (3 stages) --------------------
__global__ __launch_bounds__(1024) void scan_local(const int* __restrict__ deg,
                                                   int* __restrict__ off,
                                                   int* __restrict__ bsum) {
  __shared__ int buf[1024];
  int b = blockIdx.x, t = threadIdx.x, i = b * 1024 + t;
  int v = (i < N_NODES) ? deg[i] : 0;
  buf[t] = v;
  __syncthreads();
  for (int d = 1; d < 1024; d <<= 1) {
    int x = (t >= d) ? buf[t - d] : 0;
    __syncthreads();
    buf[t] += x;
    __syncthreads();
  }
  if (i < N_NODES) off[i] = buf[t] - v;     // exclusive (local)
  if (t == 1023) bsum[b] = buf[t];
}

__global__ void scan_bsums(const int* __restrict__ bsum, int* __restrict__ bscan,
                           int* __restrict__ offN) {
  int t = threadIdx.x;                      // 64 threads, 1 block
  int v = (t < NBLK_SCAN) ? bsum[t] : 0;
  int orig = v;
  for (int d = 1; d < 64; d <<= 1) {
    int x = __shfl_up(v, d);
    if (t >= d) v += x;
  }
  if (t < NBLK_SCAN) bscan[t] = v - orig;   // exclusive
  if (t == NBLK_SCAN - 1) offN[0] = v;      // total == N_EDGES
}

__global__ void add_bscan(int* __restrict__ off, const int* __restrict__ bscan) {
  int i = blockIdx.x * 256 + threadIdx.x;
  if (i < N_NODES) off[i] += bscan[i >> 10];
}

// ---------------- K5: scatter edges into CSR + edge score (int2 packed) -----
__global__ void scatter_edges(const int* __restrict__ src, const int* __restrict__ dst,
                              const float* __restrict__ el, const float* __restrict__ er,
                              const int* __restrict__ off, int* __restrict__ cnt,
                              int2* __restrict__ sed) {
  int e = blockIdx.x * blockDim.x + threadIdx.x;
  if (e >= N_EDGES) return;
  int s = src[e], d = dst[e];
  int pos = off[d] + atomicAdd(&cnt[d], 1);
  float ev = el[s] + er[d];
  ev = (ev > 0.f ? ev : 0.f) + 1.0f;
  int2 pv; pv.x = s; pv.y = __float_as_int(ev);
  sed[pos] = pv;
}

// ---------------- K6: fused single-pass softmax + aggregation ---------------
__global__ __launch_bounds__(256) void aggregate(const int* __restrict__ off,
                         const int2* __restrict__ sed,
                         const unsigned short* __restrict__ ftb,
                         float* __restrict__ out) {
  int node = (int)((blockIdx.x * blockDim.x + threadIdx.x) >> 6);
  int lane = threadIdx.x & 63;
  if (node >= N_NODES) return;
  int start = off[node], end = off[node + 1];

  f32x4 a0 = (f32x4)0.f, a1 = (f32x4)0.f, a2 = (f32x4)0.f, a3 = (f32x4)0.f;
  float d0 = 0.f, d1 = 0.f, d2 = 0.f, d3 = 0.f;

  int i = start;
  for (; i + 4 <= end; i += 4) {
    int2 e0 = sed[i], e1 = sed[i + 1], e2 = sed[i + 2], e3 = sed[i + 3];
    uint2 v0 = *((const uint2*)(ftb + (size_t)e0.x * OUT_DIM) + lane);
    uint2 v1 = *((const uint2*)(ftb + (size_t)e1.x * OUT_DIM) + lane);
    uint2 v2 = *((const uint2*)(ftb + (size_t)e2.x * OUT_DIM) + lane);
    uint2 v3 = *((const uint2*)(ftb + (size_t)e3.x * OUT_DIM) + lane);
    float w0 = __expf(__int_as_float(e0.y));
    float w1 = __expf(__int_as_float(e1.y));
    float w2 = __expf(__int_as_float(e2.y));
    float w3 = __expf(__int_as_float(e3.y));
    d0 += w0; d1 += w1; d2 += w2; d3 += w3;
    a0[0] += w0 * bf2f((unsigned short)(v0.x & 0xFFFF));
    a0[1] += w0 * bf2f((unsigned short)(v0.x >> 16));
    a0[2] += w0 * bf2f((unsigned short)(v0.y & 0xFFFF));
    a0[3] += w0 * bf2f((unsigned short)(v0.y >> 16));
    a1[0] += w1 * bf2f((unsigned short)(v1.x & 0xFFFF));
    a1[1] += w1 * bf2f((unsigned short)(v1.x >> 16));
    a1[2] += w1 * bf2f((unsigned short)(v1.y & 0xFFFF));
    a1[3] += w1 * bf2f((unsigned short)(v1.y >> 16));
    a2[0] += w2 * bf2f((unsigned short)(v2.x & 0xFFFF));
    a2[1] += w2 * bf2f((unsigned short)(v2.x >> 16));
    a2[2] += w2 * bf2f((unsigned short)(v2.y & 0xFFFF));
    a2[3] += w2 * bf2f((unsigned short)(v2.y >> 16));
    a3[0] += w3 * bf2f((unsigned short)(v3.x & 0xFFFF));
    a3[1] += w3 * bf2f((unsigned short)(v3.x >> 16));
    a3[2] += w3 * bf2f((unsigned short)(v3.y & 0xFFFF));
    a3[3] += w3 * bf2f((unsigned short)(v3.y >> 16));
  }
  for (; i < end; ++i) {
    int2 e0 = sed[i];
    uint2 v0 = *((const uint2*)(ftb + (size_t)e0.x * OUT_DIM) + lane);
    float w0 = __expf(__int_as_float(e0.y));
    d0 += w0;
    a0[0] += w0 * bf2f((unsigned short)(v0.x & 0xFFFF));
    a0[1] += w0 * bf2f((unsigned short)(v0.x >> 16));
    a0[2] += w0 * bf2f((unsigned short)(v0.y & 0xFFFF));
    a0[3] += w0 * bf2f((unsigned short)(v0.y >> 16));
  }

  f32x4 acc = (a0 + a1) + (a2 + a3);
  float dsum = (d0 + d1) + (d2 + d3);
  float inv = (end > start) ? 1.0f / dsum : 0.f;
  acc *= inv;
  __builtin_nontemporal_store(acc, (f32x4*)(out + (size_t)node * OUT_DIM + lane * 4));
}

// ---------------- launch ----------------------------------------------------
extern "C" void kernel_launch(void* const* d_in, const int* in_sizes, int n_in,
                              void* d_out, int out_size, void* d_ws, size_t ws_size,
                              hipStream_t stream) {
  const float* feat = (const float*)d_in[0];
  // d_in[1] = p (unused in eval path)
  const float* Wl = (const float*)d_in[2];
  const float* bl = (const float*)d_in[3];
  const float* Wr = (const float*)d_in[4];
  const float* br = (const float*)d_in[5];
  const float* W  = (const float*)d_in[6];
  const float* b  = (const float*)d_in[7];
  const int* src  = (const int*)d_in[8];
  const int* dst  = (const int*)d_in[9];
  float* out = (float*)d_out;

  char* ws = (char*)d_ws;
  float* el = (float*)ws;            ws += (size_t)N_NODES * 4;
  float* er = (float*)ws;            ws += (size_t)N_NODES * 4;
  unsigned short* Wtp = (unsigned short*)ws;  ws += (size_t)OUT_DIM * IN_DIM * 2;
  unsigned short* ftb = (unsigned short*)ws;  ws += (size_t)N_NODES * OUT_DIM * 2;
  int* deg  = (int*)ws;              ws += (size_t)N_NODES * 4;
  int* cnt  = (int*)ws;              ws += (size_t)N_NODES * 4;
  int* off  = (int*)ws;              ws += (size_t)(N_NODES + 1) * 4;
  int2* sed = (int2*)ws;             ws += (size_t)N_EDGES * 8;
  int* bsum = (int*)ws;              ws += 64 * 4;
  int* bscan = (int*)ws;             ws += 64 * 4;

  hipMemsetAsync(deg, 0, (size_t)N_NODES * 4 * 2, stream);   // deg + cnt

  // allow 128 KB dynamic LDS (host-side, graph-capture-safe, idempotent)
  hipFuncSetAttribute((const void*)gemm_mfma,
                      hipFuncAttributeMaxDynamicSharedMemorySize, 131072);

  wconv<<<(OUT_DIM * IN_DIM) / 256, 256, 0, stream>>>(W, Wtp);
  gemm_mfma<<<(N_NODES + GBM - 1) / GBM, 512, 131072, stream>>>(feat, Wtp, b,
                                                    Wl, bl, Wr, br, ftb, el, er);
  deg_count<<<(N_EDGES + 255) / 256, 256, 0, stream>>>(dst, deg);
  scan_local<<<NBLK_SCAN, 1024, 0, stream>>>(deg, off, bsum);
  scan_bsums<<<1, 64, 0, stream>>>(bsum, bscan, off + N_NODES);
  add_bscan<<<(N_NODES + 255) / 256, 256, 0, stream>>>(off, bscan);
  scatter_edges<<<(N_EDGES + 255) / 256, 256, 0, stream>>>(src, dst, el, er, off, cnt, sed);
  aggregate<<<(N_NODES + 3) / 4, 256, 0, stream>>>(off, sed, ftb, out);
}